// Round 8
// baseline (982.661 us; speedup 1.0000x reference)
//
#include <hip/hip_runtime.h>
#include <hip/hip_bf16.h>

typedef unsigned short u16;
typedef unsigned int u32;

typedef __bf16 bf16x8 __attribute__((ext_vector_type(8)));
typedef float f32x4 __attribute__((ext_vector_type(4)));

__device__ __forceinline__ float b2f(u16 u) { return __uint_as_float(((u32)u) << 16); }
__device__ __forceinline__ float b2f_lo(u32 u) { return __uint_as_float(u << 16); }
__device__ __forceinline__ float b2f_hi(u32 u) { return __uint_as_float(u & 0xffff0000u); }
__device__ __forceinline__ u16 f2b(float f) {
    u32 u = __float_as_uint(f);
    u32 r = u + 0x7fffu + ((u >> 16) & 1u);   // round-to-nearest-even
    return (u16)(r >> 16);
}

// ---------------- small utility kernels ----------------

__global__ void softmax_small(const float* __restrict__ att, float* __restrict__ mask, int K) {
    if (threadIdx.x == 0) {
        float m = -3.4e38f;
        for (int i = 0; i < K; ++i) m = fmaxf(m, att[i]);
        float s = 0.f;
        for (int i = 0; i < K; ++i) { float e = __expf(att[i] - m); mask[i] = e; s += e; }
        for (int i = 0; i < K; ++i) mask[i] /= s;
    }
}

__global__ void pack_bf16(const float* __restrict__ src, u16* __restrict__ dst, long n) {
    long g = (long)blockIdx.x * 256 + threadIdx.x;   // one float4 per thread
    if (g * 4 >= n) return;
    float4 v = reinterpret_cast<const float4*>(src)[g];
    ushort4 o;
    o.x = f2b(v.x); o.y = f2b(v.y); o.z = f2b(v.z); o.w = f2b(v.w);
    reinterpret_cast<ushort4*>(dst)[g] = o;
}

// transpose-pack f32 W[K][Nc] -> bf16 Wt[Nc][K]
__global__ void pack_wt(const float* __restrict__ W, u16* __restrict__ Wt, int K, int Nc) {
    int idx = blockIdx.x * 256 + threadIdx.x;
    if (idx >= K * Nc) return;
    int n = idx / K, k = idx - n * K;
    Wt[idx] = f2b(W[(size_t)k * Nc + n]);
}

// pack Wc [NB*256][O] -> per-branch transposed bf16 [NB][48][256], zero-padded cols
__global__ void pack_wct(const float* __restrict__ Wc, u16* __restrict__ Wct, int O, int NB) {
    int idx = blockIdx.x * 256 + threadIdx.x;
    if (idx >= NB * 48 * 256) return;
    int b = idx / (48 * 256);
    int r = idx - b * 48 * 256;
    int n = r >> 8, k = r & 255;
    float v = (n < O) ? Wc[((size_t)(b * 256 + k)) * O + n] : 0.f;
    Wct[idx] = f2b(v);
}

// ---------------- bucket-local CSR build (no global random atomics) ----------------
#define BSHIFT 8
#define BMAX 256          // N <= 65536 -> at most 256 buckets
#define BCAP 12288        // fixed bucket capacity; mean E/B ~8163, sigma ~90
#define BINCHUNK 16384

// phase 1: per-block LDS bucket histogram -> one reservation atomic per bucket ->
// packed (dlocal<<16 | src) writes into the bucket's fixed-capacity region.
__global__ __launch_bounds__(256) void bin_edges(
    const int* __restrict__ ei, const int* __restrict__ nei, int E, int B,
    int* __restrict__ bcnt, u32* __restrict__ binned) {
    int set = blockIdx.y;
    const int* src = (set == 0) ? ei : (nei + (size_t)(set - 1) * 2 * E);
    const int* dst = src + E;
    __shared__ int hist[BMAX], resv[BMAX], lcur[BMAX];
    int t = threadIdx.x;
    hist[t] = 0; lcur[t] = 0;
    __syncthreads();
    int base = blockIdx.x * BINCHUNK;
    int lim = min(base + BINCHUNK, E);
    for (int i = base + t; i < lim; i += 256)
        atomicAdd(&hist[dst[i] >> BSHIFT], 1);
    __syncthreads();
    if (t < B && hist[t] > 0) resv[t] = atomicAdd(&bcnt[set * BMAX + t], hist[t]);
    __syncthreads();
    for (int i = base + t; i < lim; i += 256) {
        int d = dst[i];
        int b = d >> BSHIFT;
        int off = resv[b] + atomicAdd(&lcur[b], 1);
        if (off < BCAP)
            binned[((size_t)set * BMAX + b) * BCAP + off] = (u32)src[i] | ((u32)(d & 255) << 16);
    }
}

// phase 2: exclusive scan of bucket totals -> bucket bases; rp[N] = E
__global__ void bscan(const int* __restrict__ bcnt, int* __restrict__ bbase,
                      int* __restrict__ rp, int N, int E, int B) {
    int set = blockIdx.x, t = threadIdx.x;
    int v = (t < B) ? bcnt[set * BMAX + t] : 0;
    __shared__ int s[256];
    s[t] = v; __syncthreads();
    for (int off = 1; off < 256; off <<= 1) {
        int x = s[t];
        int add = (t >= off) ? s[t - off] : 0;
        __syncthreads();
        s[t] = x + add;
        __syncthreads();
    }
    bbase[set * BMAX + t] = s[t] - v;
    if (t == 0) rp[(size_t)set * (N + 1) + N] = E;
}

// phase 3: one block per (set,bucket). LDS degree histogram -> dinv + rp
// (coalesced writes), then scatter colAll with LDS cursors into the bucket's
// contiguous span (single-XCD L2-resident).
__global__ __launch_bounds__(256) void bucket_build(
    const u32* __restrict__ binned, const int* __restrict__ bcnt,
    const int* __restrict__ bbase, int* __restrict__ rp, float* __restrict__ dinv,
    int* __restrict__ colAll, int E, int N) {
    int set = blockIdx.y;
    int b = blockIdx.x;
    int t = threadIdx.x;
    int nb = bcnt[set * BMAX + b];
    int base = bbase[set * BMAX + b];
    const u32* bin = binned + ((size_t)set * BMAX + b) * BCAP;
    __shared__ int s[256], lcur[256];
    s[t] = 0; lcur[t] = 0;
    __syncthreads();
    for (int i = t; i < nb; i += 256)
        atomicAdd(&s[bin[i] >> 16], 1);
    __syncthreads();
    int deg = s[t];
    __syncthreads();
    // Hillis-Steele inclusive scan -> exclusive prefix in s
    for (int off = 1; off < 256; off <<= 1) {
        int x = s[t];
        int add = (t >= off) ? s[t - off] : 0;
        __syncthreads();
        s[t] = x + add;
        __syncthreads();
    }
    int ex = s[t] - deg;
    __syncthreads();
    s[t] = ex;
    int node = (b << BSHIFT) + t;
    if (node < N) {
        rp[(size_t)set * (N + 1) + node] = base + ex;
        dinv[(size_t)set * N + node] = rsqrtf((float)(deg + 1));
    }
    __syncthreads();
    for (int i = t; i < nb; i += 256) {
        u32 pk = bin[i];
        int dl = (int)(pk >> 16);
        int pos = base + s[dl] + atomicAdd(&lcur[dl], 1);
        colAll[(size_t)set * E + pos] = (int)(pk & 0xffffu);
    }
}

// ---------------- main GEMM: [M,256] x [256,256] (Bt transposed) ----------------
// MODE 0: out = relu(acc + bias[col]) * mask[maskIdx]   (mlp branch)
// MODE 1: out = acc * dinv[row]                         (pre-aggregation scale)
#define SA 72   // LDS row stride in bf16 elems (64 + 8 pad)

template <int MODE>
__global__ __launch_bounds__(256) void gemm_k256(
    const u16* __restrict__ A, const u16* __restrict__ Bt, u16* __restrict__ out,
    const float* __restrict__ bias, const float* __restrict__ dinv,
    const float* __restrict__ maskp, int maskIdx, int M) {
    __shared__ alignas(16) u16 lsA[128 * SA];
    __shared__ alignas(16) u16 lsB[128 * SA];
    const int tid = threadIdx.x;
    const int rowBase = blockIdx.x * 128;
    const int colBase = blockIdx.y * 128;
    const int w = tid >> 6, l = tid & 63;
    const int wm = w >> 1, wn = w & 1;
    const int lrow = l & 15, lkg = l >> 4;
    f32x4 acc[4][4] = {};

    for (int kt = 0; kt < 4; ++kt) {
        const int k0 = kt * 64;
#pragma unroll
        for (int q = 0; q < 4; ++q) {                 // 1024 16B granules per tile
            int g = q * 256 + tid;
            int m = g >> 3, gq = g & 7;               // 8 granules (64 bf16) per row
            int grow = rowBase + m;
            uint4 v = make_uint4(0, 0, 0, 0);
            if (grow < M)
                v = *reinterpret_cast<const uint4*>(A + (size_t)grow * 256 + k0 + gq * 8);
            *reinterpret_cast<uint4*>(&lsA[m * SA + gq * 8]) = v;
            uint4 vb = *reinterpret_cast<const uint4*>(Bt + (size_t)(colBase + m) * 256 + k0 + gq * 8);
            *reinterpret_cast<uint4*>(&lsB[m * SA + gq * 8]) = vb;
        }
        __syncthreads();
#pragma unroll
        for (int kk = 0; kk < 2; ++kk) {
            bf16x8 af[4], bfr[4];
            int kg8 = (kk * 4 + lkg) * 8;
#pragma unroll
            for (int mf = 0; mf < 4; ++mf)
                af[mf] = *reinterpret_cast<const bf16x8*>(&lsA[(wm * 64 + mf * 16 + lrow) * SA + kg8]);
#pragma unroll
            for (int nf = 0; nf < 4; ++nf)
                bfr[nf] = *reinterpret_cast<const bf16x8*>(&lsB[(wn * 64 + nf * 16 + lrow) * SA + kg8]);
#pragma unroll
            for (int mf = 0; mf < 4; ++mf)
#pragma unroll
                for (int nf = 0; nf < 4; ++nf)
                    acc[mf][nf] = __builtin_amdgcn_mfma_f32_16x16x32_bf16(af[mf], bfr[nf], acc[mf][nf], 0, 0, 0);
        }
        __syncthreads();
    }

    float mk = 1.f;
    if (MODE == 0) mk = maskp[maskIdx];
#pragma unroll
    for (int mf = 0; mf < 4; ++mf) {
#pragma unroll
        for (int r = 0; r < 4; ++r) {
            int row = rowBase + wm * 64 + mf * 16 + lkg * 4 + r;
            if (row >= M) continue;
            float dv = (MODE == 1) ? dinv[row] : 0.f;
#pragma unroll
            for (int nf = 0; nf < 4; ++nf) {
                int colG = colBase + wn * 64 + nf * 16 + lrow;
                float v = acc[mf][nf][r];
                if (MODE == 0) v = fmaxf(v + bias[colG], 0.f) * mk;
                else           v = v * dv;
                out[(size_t)row * 256 + colG] = f2b(v);
            }
        }
    }
}

// ---------------- CSR gather aggregation ----------------
// One wave per node; lanes 0-31 take even-indexed neighbors, lanes 32-63 odd.
// Each lane loads uint4 (16B = 8 channels): one load instruction covers TWO
// neighbor rows -> half the VMEM instruction count of the 8B/lane version.
// Cross-half combine via shfl_xor(32) at the end.
__global__ __launch_bounds__(256) void agg_gcn(
    const u16* __restrict__ hp, const int* __restrict__ rp, const int* __restrict__ colv,
    const float* __restrict__ dinv, const float* __restrict__ bias,
    const float* __restrict__ maskp, int maskIdx, u16* __restrict__ outb, int N) {
    int node = blockIdx.x * 4 + (threadIdx.x >> 6);
    if (node >= N) return;
    const int l = threadIdx.x & 63;
    const int h = l >> 5;          // half index: 0 = even neighbors, 1 = odd
    const int li = l & 31;         // lane-in-half: granule index (8 ch each)
    const uint4* hv = reinterpret_cast<const uint4*>(hp);   // row = 32 uint4
    float a[8] = {0.f, 0.f, 0.f, 0.f, 0.f, 0.f, 0.f, 0.f};

    // self-loop term: counted once (half 0 only)
    {
        uint4 v = hv[(size_t)node * 32 + li];
        if (h == 0) {
            a[0] += b2f_lo(v.x); a[1] += b2f_hi(v.x);
            a[2] += b2f_lo(v.y); a[3] += b2f_hi(v.y);
            a[4] += b2f_lo(v.z); a[5] += b2f_hi(v.z);
            a[6] += b2f_lo(v.w); a[7] += b2f_hi(v.w);
        }
    }

    int beg = rp[node], end = rp[node + 1];
    int j = beg;
    // 16 neighbors per iteration via 8 dual-row loads
    for (; j + 16 <= end; j += 16) {
        int s[8];
#pragma unroll
        for (int q = 0; q < 8; ++q) s[q] = colv[j + 2 * q + h];
        uint4 v[8];
#pragma unroll
        for (int q = 0; q < 8; ++q) v[q] = hv[(size_t)s[q] * 32 + li];
#pragma unroll
        for (int q = 0; q < 8; ++q) {
            a[0] += b2f_lo(v[q].x); a[1] += b2f_hi(v[q].x);
            a[2] += b2f_lo(v[q].y); a[3] += b2f_hi(v[q].y);
            a[4] += b2f_lo(v[q].z); a[5] += b2f_hi(v[q].z);
            a[6] += b2f_lo(v[q].w); a[7] += b2f_hi(v[q].w);
        }
    }
    // pair tail
    for (; j + 2 <= end; j += 2) {
        int s = colv[j + h];
        uint4 v = hv[(size_t)s * 32 + li];
        a[0] += b2f_lo(v.x); a[1] += b2f_hi(v.x);
        a[2] += b2f_lo(v.y); a[3] += b2f_hi(v.y);
        a[4] += b2f_lo(v.z); a[5] += b2f_hi(v.z);
        a[6] += b2f_lo(v.w); a[7] += b2f_hi(v.w);
    }
    // odd final neighbor: counted once (half 0 only)
    if (j < end) {
        int s = colv[j];
        uint4 v = hv[(size_t)s * 32 + li];
        if (h == 0) {
            a[0] += b2f_lo(v.x); a[1] += b2f_hi(v.x);
            a[2] += b2f_lo(v.y); a[3] += b2f_hi(v.y);
            a[4] += b2f_lo(v.z); a[5] += b2f_hi(v.z);
            a[6] += b2f_lo(v.w); a[7] += b2f_hi(v.w);
        }
    }

    // combine halves: lane l ^ 32 holds the other parity's partial sums
#pragma unroll
    for (int q = 0; q < 8; ++q) a[q] += __shfl_xor(a[q], 32);

    if (h == 0) {
        float dv = dinv[node];
        float mk = (maskIdx >= 0) ? maskp[maskIdx] : 1.f;
        int ch = li * 8;
        u32 o[4];
#pragma unroll
        for (int q = 0; q < 4; ++q) {
            float e0 = fmaxf(fmaf(a[2 * q + 0], dv, bias[ch + 2 * q + 0]), 0.f) * mk;
            float e1 = fmaxf(fmaf(a[2 * q + 1], dv, bias[ch + 2 * q + 1]), 0.f) * mk;
            o[q] = (u32)f2b(e0) | ((u32)f2b(e1) << 16);
        }
        uint4 ov = make_uint4(o[0], o[1], o[2], o[3]);
        reinterpret_cast<uint4*>(outb)[(size_t)node * 32 + li] = ov;
    }
}

// ---------------- logits ----------------

__global__ void init_logits(float* __restrict__ out, const float* __restrict__ bc, long total, int O) {
    long i = (long)blockIdx.x * 256 + threadIdx.x;
    if (i < total) out[i] = bc[(int)(i % O)];
}

// out[M][40] += A[M][256](bf16) x Wct[48][256](bf16, transposed, zero-padded)
__global__ __launch_bounds__(256) void logit_gemm(const u16* __restrict__ A,
                                                  const u16* __restrict__ Wct,
                                                  float* __restrict__ out, int M) {
    int l = threadIdx.x & 63;
    int rowBase = blockIdx.x * 64 + (threadIdx.x >> 6) * 16;
    if (rowBase >= M) return;
    int lrow = l & 15, lkg = l >> 4;
    int ar = rowBase + lrow; if (ar >= M) ar = M - 1;
    f32x4 acc[3] = {};
#pragma unroll
    for (int kt = 0; kt < 8; ++kt) {
        bf16x8 a = *reinterpret_cast<const bf16x8*>(A + (size_t)ar * 256 + kt * 32 + lkg * 8);
#pragma unroll
        for (int nf = 0; nf < 3; ++nf) {
            bf16x8 b = *reinterpret_cast<const bf16x8*>(Wct + (size_t)(nf * 16 + lrow) * 256 + kt * 32 + lkg * 8);
            acc[nf] = __builtin_amdgcn_mfma_f32_16x16x32_bf16(a, b, acc[nf], 0, 0, 0);
        }
    }
#pragma unroll
    for (int nf = 0; nf < 3; ++nf) {
        int col = nf * 16 + lrow;
        if (col < 40) {
#pragma unroll
            for (int r = 0; r < 4; ++r) {
                int row = rowBase + lkg * 4 + r;
                if (row < M) out[(size_t)row * 40 + col] += acc[nf][r];
            }
        }
    }
}

__global__ void logsoftmax_k(float* __restrict__ out, int M, int O) {
    int row = blockIdx.x * 4 + (threadIdx.x >> 6);
    if (row >= M) return;
    int l = threadIdx.x & 63;
    float v = (l < O) ? out[(size_t)row * O + l] : -3.4e38f;
    float m = v;
    for (int off = 32; off; off >>= 1) m = fmaxf(m, __shfl_xor(m, off));
    float e = (l < O) ? __expf(v - m) : 0.f;
    float s = e;
    for (int off = 32; off; off >>= 1) s += __shfl_xor(s, off);
    if (l < O) out[(size_t)row * O + l] = v - m - __logf(s);
}

// ---------------- host launch ----------------

extern "C" void kernel_launch(void* const* d_in, const int* in_sizes, int n_in,
                              void* d_out, int out_size, void* d_ws, size_t ws_size,
                              hipStream_t stream) {
    (void)n_in; (void)out_size; (void)ws_size;
    const float* x     = (const float*)d_in[0];
    const int*   ei    = (const int*)d_in[1];
    const int*   nei   = (const int*)d_in[2];
    const float* W_mlp = (const float*)d_in[3];
    const float* b_mlp = (const float*)d_in[4];
    const float* We1   = (const float*)d_in[5];
    const float* be1   = (const float*)d_in[6];
    const float* We2   = (const float*)d_in[7];
    const float* be2   = (const float*)d_in[8];
    const float* Wh    = (const float*)d_in[9];
    const float* bh    = (const float*)d_in[10];
    const float* att   = (const float*)d_in[11];
    const float* Wc    = (const float*)d_in[12];
    const float* bc    = (const float*)d_in[13];
    float* out = (float*)d_out;

    const int N    = in_sizes[0] / 256;     // 50000 (< 65536: u16 pack valid)
    const int E    = in_sizes[1] / 2;       // 1600000
    const int HOPS = in_sizes[10] / 256;    // 3
    const int O    = in_sizes[13];          // 40
    const int SETS = HOPS + 1;              // edge sets: [ei, hop0..2]
    const int NB   = HOPS + 2;              // branches
    const int B    = (N + 255) >> 8;        // buckets (<= 256)

    // workspace carve (256B aligned)
    char* p = (char*)d_ws;
    auto carve = [&](size_t bytes) { char* r = p; p += (bytes + 255) & ~(size_t)255; return r; };
    u16* x16  = (u16*)carve((size_t)N * 256 * 2);
    u16* hA   = (u16*)carve((size_t)N * 256 * 2);
    u16* hB   = (u16*)carve((size_t)N * 256 * 2);
    u16* ebuf = (u16*)carve((size_t)N * 256 * 2);
    u16* wt   = (u16*)carve((size_t)(3 + HOPS) * 256 * 256 * 2); // [mlp,e1,e2,hop0..]
    u16* wct  = (u16*)carve((size_t)NB * 48 * 256 * 2);
    float* mask = (float*)carve(256);
    float* dinv = (float*)carve((size_t)SETS * N * 4);
    int* rp   = (int*)carve((size_t)SETS * (N + 1) * 4);
    int* bcnt = (int*)carve((size_t)SETS * BMAX * 4);
    int* bbase = (int*)carve((size_t)SETS * BMAX * 4);
    int* colAll = (int*)carve((size_t)SETS * E * 4);
    u32* binned = (u32*)hA;   // alias hA+hB (51.2MB >= SETS*BMAX*BCAP*4 = 50.3MB);
                              // binned lifetime ends before any GEMM writes hA/hB

    // packing + mask
    softmax_small<<<1, 64, 0, stream>>>(att, mask, NB);
    {
        long n = (long)N * 256;
        pack_bf16<<<(int)((n / 4 + 255) / 256), 256, 0, stream>>>(x, x16, n);
    }
    pack_wt<<<256, 256, 0, stream>>>(W_mlp, wt + 0 * 65536, 256, 256);
    pack_wt<<<256, 256, 0, stream>>>(We1,   wt + 1 * 65536, 256, 256);
    pack_wt<<<256, 256, 0, stream>>>(We2,   wt + 2 * 65536, 256, 256);
    for (int i = 0; i < HOPS; ++i)
        pack_wt<<<256, 256, 0, stream>>>(Wh + (size_t)i * 65536, wt + (size_t)(3 + i) * 65536, 256, 256);
    {
        int tot = NB * 48 * 256;
        pack_wct<<<(tot + 255) / 256, 256, 0, stream>>>(Wc, wct, O, NB);
    }

    // bucket-local CSR build
    hipMemsetAsync(bcnt, 0, (size_t)SETS * BMAX * 4, stream);
    {
        dim3 g((E + BINCHUNK - 1) / BINCHUNK, SETS);
        bin_edges<<<g, 256, 0, stream>>>(ei, nei, E, B, bcnt, binned);
    }
    bscan<<<SETS, 256, 0, stream>>>(bcnt, bbase, rp, N, E, B);
    {
        dim3 g(B, SETS);
        bucket_build<<<g, 256, 0, stream>>>(binned, bcnt, bbase, rp, dinv, colAll, E, N);
    }

    // logits = bc
    {
        long tot = (long)N * O;
        init_logits<<<(int)((tot + 255) / 256), 256, 0, stream>>>(out, bc, tot, O);
    }

    dim3 gg((N + 127) / 128, 2);
    const int gl = (N + 63) / 64;
    const int ga = (N + 3) / 4;

    // mlp branch -> Wc block NB-1
    gemm_k256<0><<<gg, 256, 0, stream>>>(x16, wt, hB, b_mlp, nullptr, mask, 0, N);
    logit_gemm<<<gl, 256, 0, stream>>>(hB, wct + (size_t)(NB - 1) * 48 * 256, out, N);

    // hop branches -> Wc blocks 0..HOPS-1, mask[i+1]
    for (int i = 0; i < HOPS; ++i) {
        int s = i + 1;
        gemm_k256<1><<<gg, 256, 0, stream>>>(x16, wt + (size_t)(3 + i) * 65536, hA,
                                             nullptr, dinv + (size_t)s * N, nullptr, 0, N);
        agg_gcn<<<ga, 256, 0, stream>>>(hA, rp + (size_t)s * (N + 1), colAll + (size_t)s * E,
                                        dinv + (size_t)s * N, bh + (size_t)i * 256,
                                        mask, i + 1, hB, N);
        logit_gemm<<<gl, 256, 0, stream>>>(hB, wct + (size_t)i * 48 * 256, out, N);
    }

    // e branch: gcn1 (no mask) -> gcn2 (*mask[1]) -> Wc block HOPS
    gemm_k256<1><<<gg, 256, 0, stream>>>(x16, wt + 1 * 65536, hA, nullptr, dinv, nullptr, 0, N);
    agg_gcn<<<ga, 256, 0, stream>>>(hA, rp, colAll, dinv, be1, mask, -1, ebuf, N);
    gemm_k256<1><<<gg, 256, 0, stream>>>(ebuf, wt + 2 * 65536, hA, nullptr, dinv, nullptr, 0, N);
    agg_gcn<<<ga, 256, 0, stream>>>(hA, rp, colAll, dinv, be2, mask, 1, hB, N);
    logit_gemm<<<gl, 256, 0, stream>>>(hB, wct + (size_t)HOPS * 48 * 256, out, N);

    // final log-softmax in place on d_out
    logsoftmax_k<<<(N + 3) / 4, 256, 0, stream>>>(out, N, O);
}

// Round 9
// 936.571 us; speedup vs baseline: 1.0492x; 1.0492x over previous
//
#include <hip/hip_runtime.h>
#include <hip/hip_bf16.h>

typedef unsigned short u16;
typedef unsigned int u32;

typedef __bf16 bf16x8 __attribute__((ext_vector_type(8)));
typedef float f32x4 __attribute__((ext_vector_type(4)));

__device__ __forceinline__ float b2f(u16 u) { return __uint_as_float(((u32)u) << 16); }
__device__ __forceinline__ float b2f_lo(u32 u) { return __uint_as_float(u << 16); }
__device__ __forceinline__ float b2f_hi(u32 u) { return __uint_as_float(u & 0xffff0000u); }
__device__ __forceinline__ u16 f2b(float f) {
    u32 u = __float_as_uint(f);
    u32 r = u + 0x7fffu + ((u >> 16) & 1u);   // round-to-nearest-even
    return (u16)(r >> 16);
}

// ---------------- small utility kernels ----------------

__global__ void softmax_small(const float* __restrict__ att, float* __restrict__ mask, int K) {
    if (threadIdx.x == 0) {
        float m = -3.4e38f;
        for (int i = 0; i < K; ++i) m = fmaxf(m, att[i]);
        float s = 0.f;
        for (int i = 0; i < K; ++i) { float e = __expf(att[i] - m); mask[i] = e; s += e; }
        for (int i = 0; i < K; ++i) mask[i] /= s;
    }
}

__global__ void pack_bf16(const float* __restrict__ src, u16* __restrict__ dst, long n) {
    long g = (long)blockIdx.x * 256 + threadIdx.x;   // one float4 per thread
    if (g * 4 >= n) return;
    float4 v = reinterpret_cast<const float4*>(src)[g];
    ushort4 o;
    o.x = f2b(v.x); o.y = f2b(v.y); o.z = f2b(v.z); o.w = f2b(v.w);
    reinterpret_cast<ushort4*>(dst)[g] = o;
}

// transpose-pack all six 256x256 f32 weights -> bf16 [6][256][256] (row = out col)
__global__ void pack_wt_all(const float* __restrict__ W_mlp, const float* __restrict__ We1,
                            const float* __restrict__ We2, const float* __restrict__ Wh,
                            u16* __restrict__ wt) {
    int idx = blockIdx.x * 256 + threadIdx.x;   // < 65536
    int y = blockIdx.y;
    const float* W = (y == 0) ? W_mlp : (y == 1) ? We1 : (y == 2) ? We2
                                      : (Wh + (size_t)(y - 3) * 65536);
    int n = idx >> 8, k = idx & 255;
    wt[(size_t)y * 65536 + idx] = f2b(W[k * 256 + n]);
}

// pack Wc [NB*256][O] -> per-branch transposed bf16 [NB][48][256], zero-padded cols
__global__ void pack_wct(const float* __restrict__ Wc, u16* __restrict__ Wct, int O, int NB) {
    int idx = blockIdx.x * 256 + threadIdx.x;
    if (idx >= NB * 48 * 256) return;
    int b = idx / (48 * 256);
    int r = idx - b * 48 * 256;
    int n = r >> 8, k = r & 255;
    float v = (n < O) ? Wc[((size_t)(b * 256 + k)) * O + n] : 0.f;
    Wct[idx] = f2b(v);
}

// ---------------- bucket-local CSR build (no global random atomics) ----------------
#define BSHIFT 8
#define BMAX 256          // N <= 65536 -> at most 256 buckets
#define BCAP 12288        // fixed bucket capacity; mean E/B ~8163
#define BINCHUNK 8192

// phase 1: LDS histogram -> one reservation atomic per bucket -> LDS bucket-sort
// of the chunk's edges -> bucket-run writes with CONSECUTIVE lanes (full-line
// coalesced stores). Entry pack: src | (d<<16) (both < 65536).
__global__ __launch_bounds__(256) void bin_edges(
    const int* __restrict__ ei, const int* __restrict__ nei, int E, int B,
    int* __restrict__ bcnt, u32* __restrict__ binned) {
    int set = blockIdx.y;
    const int* src = (set == 0) ? ei : (nei + (size_t)(set - 1) * 2 * E);
    const int* dst = src + E;
    __shared__ u32 ebuf[BINCHUNK];
    __shared__ int hist[BMAX], resv[BMAX], lbase[BMAX], lcur[BMAX], s[BMAX];
    int t = threadIdx.x;
    hist[t] = 0; lcur[t] = 0;
    __syncthreads();
    int base = blockIdx.x * BINCHUNK;
    int lim = min(base + BINCHUNK, E);
    for (int i = base + t; i < lim; i += 256)
        atomicAdd(&hist[dst[i] >> BSHIFT], 1);
    __syncthreads();
    int h = hist[t];
    if (h > 0) resv[t] = atomicAdd(&bcnt[set * BMAX + t], h);
    s[t] = h;
    __syncthreads();
    for (int off = 1; off < 256; off <<= 1) {
        int x = s[t];
        int add = (t >= off) ? s[t - off] : 0;
        __syncthreads();
        s[t] = x + add;
        __syncthreads();
    }
    lbase[t] = s[t] - h;
    __syncthreads();
    // LDS bucket-sort
    for (int i = base + t; i < lim; i += 256) {
        int d = dst[i];
        int b = d >> BSHIFT;
        int p = atomicAdd(&lcur[b], 1);
        ebuf[lbase[b] + p] = (u32)src[i] | ((u32)d << 16);
    }
    __syncthreads();
    // coalesced bucket-run writes
    int cnt = lim - base;
    for (int i = t; i < cnt; i += 256) {
        u32 pk = ebuf[i];
        int b = (int)(pk >> (16 + BSHIFT));
        int gpos = resv[b] + (i - lbase[b]);
        if (gpos < BCAP)
            binned[((size_t)set * BMAX + b) * BCAP + gpos] = pk;
    }
}

// phase 2: exclusive scan of bucket totals -> bucket bases; rp[N] = E
__global__ void bscan(const int* __restrict__ bcnt, int* __restrict__ bbase,
                      int* __restrict__ rp, int N, int E, int B) {
    int set = blockIdx.x, t = threadIdx.x;
    int v = (t < B) ? bcnt[set * BMAX + t] : 0;
    __shared__ int s[256];
    s[t] = v; __syncthreads();
    for (int off = 1; off < 256; off <<= 1) {
        int x = s[t];
        int add = (t >= off) ? s[t - off] : 0;
        __syncthreads();
        s[t] = x + add;
        __syncthreads();
    }
    bbase[set * BMAX + t] = s[t] - v;
    if (t == 0) rp[(size_t)set * (N + 1) + N] = E;
}

// phase 3: one block per (set,bucket). LDS degree histogram -> dinv + rp
// (coalesced writes), then scatter colAll with LDS cursors into the bucket's
// contiguous span (single-XCD L2-resident).
__global__ __launch_bounds__(256) void bucket_build(
    const u32* __restrict__ binned, const int* __restrict__ bcnt,
    const int* __restrict__ bbase, int* __restrict__ rp, float* __restrict__ dinv,
    int* __restrict__ colAll, int E, int N) {
    int set = blockIdx.y;
    int b = blockIdx.x;
    int t = threadIdx.x;
    int nb = bcnt[set * BMAX + b];
    int base = bbase[set * BMAX + b];
    const u32* bin = binned + ((size_t)set * BMAX + b) * BCAP;
    __shared__ int s[256], lcur[256];
    s[t] = 0; lcur[t] = 0;
    __syncthreads();
    for (int i = t; i < nb; i += 256)
        atomicAdd(&s[(bin[i] >> 16) & 255], 1);
    __syncthreads();
    int deg = s[t];
    __syncthreads();
    // Hillis-Steele inclusive scan -> exclusive prefix in s
    for (int off = 1; off < 256; off <<= 1) {
        int x = s[t];
        int add = (t >= off) ? s[t - off] : 0;
        __syncthreads();
        s[t] = x + add;
        __syncthreads();
    }
    int ex = s[t] - deg;
    __syncthreads();
    s[t] = ex;
    int node = (b << BSHIFT) + t;
    if (node < N) {
        rp[(size_t)set * (N + 1) + node] = base + ex;
        dinv[(size_t)set * N + node] = rsqrtf((float)(deg + 1));
    }
    __syncthreads();
    for (int i = t; i < nb; i += 256) {
        u32 pk = bin[i];
        int dl = (int)((pk >> 16) & 255);
        int pos = base + s[dl] + atomicAdd(&lcur[dl], 1);
        colAll[(size_t)set * E + pos] = (int)(pk & 0xffffu);
    }
}

// ---------------- main GEMM: [M,256] x [256,256] (Bt transposed) ----------------
// MODE 0: out = relu(acc + bias[col]) * mask[maskIdx]   (mlp branch)
// MODE 1: out = acc * dinv[row]                         (pre-aggregation scale)
#define SA 72   // LDS row stride in bf16 elems (64 + 8 pad)

template <int MODE>
__global__ __launch_bounds__(256) void gemm_k256(
    const u16* __restrict__ A, const u16* __restrict__ Bt, u16* __restrict__ out,
    const float* __restrict__ bias, const float* __restrict__ dinv,
    const float* __restrict__ maskp, int maskIdx, int M) {
    __shared__ alignas(16) u16 lsA[128 * SA];
    __shared__ alignas(16) u16 lsB[128 * SA];
    const int tid = threadIdx.x;
    const int rowBase = blockIdx.x * 128;
    const int colBase = blockIdx.y * 128;
    const int w = tid >> 6, l = tid & 63;
    const int wm = w >> 1, wn = w & 1;
    const int lrow = l & 15, lkg = l >> 4;
    f32x4 acc[4][4] = {};

    for (int kt = 0; kt < 4; ++kt) {
        const int k0 = kt * 64;
#pragma unroll
        for (int q = 0; q < 4; ++q) {                 // 1024 16B granules per tile
            int g = q * 256 + tid;
            int m = g >> 3, gq = g & 7;               // 8 granules (64 bf16) per row
            int grow = rowBase + m;
            uint4 v = make_uint4(0, 0, 0, 0);
            if (grow < M)
                v = *reinterpret_cast<const uint4*>(A + (size_t)grow * 256 + k0 + gq * 8);
            *reinterpret_cast<uint4*>(&lsA[m * SA + gq * 8]) = v;
            uint4 vb = *reinterpret_cast<const uint4*>(Bt + (size_t)(colBase + m) * 256 + k0 + gq * 8);
            *reinterpret_cast<uint4*>(&lsB[m * SA + gq * 8]) = vb;
        }
        __syncthreads();
#pragma unroll
        for (int kk = 0; kk < 2; ++kk) {
            bf16x8 af[4], bfr[4];
            int kg8 = (kk * 4 + lkg) * 8;
#pragma unroll
            for (int mf = 0; mf < 4; ++mf)
                af[mf] = *reinterpret_cast<const bf16x8*>(&lsA[(wm * 64 + mf * 16 + lrow) * SA + kg8]);
#pragma unroll
            for (int nf = 0; nf < 4; ++nf)
                bfr[nf] = *reinterpret_cast<const bf16x8*>(&lsB[(wn * 64 + nf * 16 + lrow) * SA + kg8]);
#pragma unroll
            for (int mf = 0; mf < 4; ++mf)
#pragma unroll
                for (int nf = 0; nf < 4; ++nf)
                    acc[mf][nf] = __builtin_amdgcn_mfma_f32_16x16x32_bf16(af[mf], bfr[nf], acc[mf][nf], 0, 0, 0);
        }
        __syncthreads();
    }

    float mk = 1.f;
    if (MODE == 0) mk = maskp[maskIdx];
#pragma unroll
    for (int mf = 0; mf < 4; ++mf) {
#pragma unroll
        for (int r = 0; r < 4; ++r) {
            int row = rowBase + wm * 64 + mf * 16 + lkg * 4 + r;
            if (row >= M) continue;
            float dv = (MODE == 1) ? dinv[row] : 0.f;
#pragma unroll
            for (int nf = 0; nf < 4; ++nf) {
                int colG = colBase + wn * 64 + nf * 16 + lrow;
                float v = acc[mf][nf][r];
                if (MODE == 0) v = fmaxf(v + bias[colG], 0.f) * mk;
                else           v = v * dv;
                out[(size_t)row * 256 + colG] = f2b(v);
            }
        }
    }
}

// ---------------- CSR gather aggregation ----------------
// One wave per node; lanes 0-31 take even-indexed neighbors, lanes 32-63 odd.
// Each lane loads uint4 (16B = 8 channels). Cross-half combine via shfl_xor(32).
__global__ __launch_bounds__(256) void agg_gcn(
    const u16* __restrict__ hp, const int* __restrict__ rp, const int* __restrict__ colv,
    const float* __restrict__ dinv, const float* __restrict__ bias,
    const float* __restrict__ maskp, int maskIdx, u16* __restrict__ outb, int N) {
    int node = blockIdx.x * 4 + (threadIdx.x >> 6);
    if (node >= N) return;
    const int l = threadIdx.x & 63;
    const int h = l >> 5;          // half index: 0 = even neighbors, 1 = odd
    const int li = l & 31;         // lane-in-half: granule index (8 ch each)
    const uint4* hv = reinterpret_cast<const uint4*>(hp);   // row = 32 uint4
    float a[8] = {0.f, 0.f, 0.f, 0.f, 0.f, 0.f, 0.f, 0.f};

    // self-loop term: counted once (half 0 only)
    {
        uint4 v = hv[(size_t)node * 32 + li];
        if (h == 0) {
            a[0] += b2f_lo(v.x); a[1] += b2f_hi(v.x);
            a[2] += b2f_lo(v.y); a[3] += b2f_hi(v.y);
            a[4] += b2f_lo(v.z); a[5] += b2f_hi(v.z);
            a[6] += b2f_lo(v.w); a[7] += b2f_hi(v.w);
        }
    }

    int beg = rp[node], end = rp[node + 1];
    int j = beg;
    for (; j + 16 <= end; j += 16) {
        int s[8];
#pragma unroll
        for (int q = 0; q < 8; ++q) s[q] = colv[j + 2 * q + h];
        uint4 v[8];
#pragma unroll
        for (int q = 0; q < 8; ++q) v[q] = hv[(size_t)s[q] * 32 + li];
#pragma unroll
        for (int q = 0; q < 8; ++q) {
            a[0] += b2f_lo(v[q].x); a[1] += b2f_hi(v[q].x);
            a[2] += b2f_lo(v[q].y); a[3] += b2f_hi(v[q].y);
            a[4] += b2f_lo(v[q].z); a[5] += b2f_hi(v[q].z);
            a[6] += b2f_lo(v[q].w); a[7] += b2f_hi(v[q].w);
        }
    }
    for (; j + 2 <= end; j += 2) {
        int s = colv[j + h];
        uint4 v = hv[(size_t)s * 32 + li];
        a[0] += b2f_lo(v.x); a[1] += b2f_hi(v.x);
        a[2] += b2f_lo(v.y); a[3] += b2f_hi(v.y);
        a[4] += b2f_lo(v.z); a[5] += b2f_hi(v.z);
        a[6] += b2f_lo(v.w); a[7] += b2f_hi(v.w);
    }
    if (j < end) {
        int s = colv[j];
        uint4 v = hv[(size_t)s * 32 + li];
        if (h == 0) {
            a[0] += b2f_lo(v.x); a[1] += b2f_hi(v.x);
            a[2] += b2f_lo(v.y); a[3] += b2f_hi(v.y);
            a[4] += b2f_lo(v.z); a[5] += b2f_hi(v.z);
            a[6] += b2f_lo(v.w); a[7] += b2f_hi(v.w);
        }
    }

#pragma unroll
    for (int q = 0; q < 8; ++q) a[q] += __shfl_xor(a[q], 32);

    if (h == 0) {
        float dv = dinv[node];
        float mk = (maskIdx >= 0) ? maskp[maskIdx] : 1.f;
        int ch = li * 8;
        u32 o[4];
#pragma unroll
        for (int q = 0; q < 4; ++q) {
            float e0 = fmaxf(fmaf(a[2 * q + 0], dv, bias[ch + 2 * q + 0]), 0.f) * mk;
            float e1 = fmaxf(fmaf(a[2 * q + 1], dv, bias[ch + 2 * q + 1]), 0.f) * mk;
            o[q] = (u32)f2b(e0) | ((u32)f2b(e1) << 16);
        }
        uint4 ov = make_uint4(o[0], o[1], o[2], o[3]);
        reinterpret_cast<uint4*>(outb)[(size_t)node * 32 + li] = ov;
    }
}

// ---------------- logits ----------------

// out[M][40] (+)= A[M][256](bf16) x Wct[48][256](bf16, transposed, zero-padded)
// FIRST=1: out = acc + bc[col] (covers every element; no init pass needed)
template <int FIRST>
__global__ __launch_bounds__(256) void logit_gemm(const u16* __restrict__ A,
                                                  const u16* __restrict__ Wct,
                                                  const float* __restrict__ bc,
                                                  float* __restrict__ out, int M) {
    int l = threadIdx.x & 63;
    int rowBase = blockIdx.x * 64 + (threadIdx.x >> 6) * 16;
    if (rowBase >= M) return;
    int lrow = l & 15, lkg = l >> 4;
    int ar = rowBase + lrow; if (ar >= M) ar = M - 1;
    f32x4 acc[3] = {};
#pragma unroll
    for (int kt = 0; kt < 8; ++kt) {
        bf16x8 a = *reinterpret_cast<const bf16x8*>(A + (size_t)ar * 256 + kt * 32 + lkg * 8);
#pragma unroll
        for (int nf = 0; nf < 3; ++nf) {
            bf16x8 b = *reinterpret_cast<const bf16x8*>(Wct + (size_t)(nf * 16 + lrow) * 256 + kt * 32 + lkg * 8);
            acc[nf] = __builtin_amdgcn_mfma_f32_16x16x32_bf16(a, b, acc[nf], 0, 0, 0);
        }
    }
#pragma unroll
    for (int nf = 0; nf < 3; ++nf) {
        int col = nf * 16 + lrow;
        if (col < 40) {
#pragma unroll
            for (int r = 0; r < 4; ++r) {
                int row = rowBase + lkg * 4 + r;
                if (row < M) {
                    if (FIRST) out[(size_t)row * 40 + col] = acc[nf][r] + bc[col];
                    else       out[(size_t)row * 40 + col] += acc[nf][r];
                }
            }
        }
    }
}

__global__ void logsoftmax_k(float* __restrict__ out, int M, int O) {
    int row = blockIdx.x * 4 + (threadIdx.x >> 6);
    if (row >= M) return;
    int l = threadIdx.x & 63;
    float v = (l < O) ? out[(size_t)row * O + l] : -3.4e38f;
    float m = v;
    for (int off = 32; off; off >>= 1) m = fmaxf(m, __shfl_xor(m, off));
    float e = (l < O) ? __expf(v - m) : 0.f;
    float s = e;
    for (int off = 32; off; off >>= 1) s += __shfl_xor(s, off);
    if (l < O) out[(size_t)row * O + l] = v - m - __logf(s);
}

// ---------------- host launch ----------------

extern "C" void kernel_launch(void* const* d_in, const int* in_sizes, int n_in,
                              void* d_out, int out_size, void* d_ws, size_t ws_size,
                              hipStream_t stream) {
    (void)n_in; (void)out_size; (void)ws_size;
    const float* x     = (const float*)d_in[0];
    const int*   ei    = (const int*)d_in[1];
    const int*   nei   = (const int*)d_in[2];
    const float* W_mlp = (const float*)d_in[3];
    const float* b_mlp = (const float*)d_in[4];
    const float* We1   = (const float*)d_in[5];
    const float* be1   = (const float*)d_in[6];
    const float* We2   = (const float*)d_in[7];
    const float* be2   = (const float*)d_in[8];
    const float* Wh    = (const float*)d_in[9];
    const float* bh    = (const float*)d_in[10];
    const float* att   = (const float*)d_in[11];
    const float* Wc    = (const float*)d_in[12];
    const float* bc    = (const float*)d_in[13];
    float* out = (float*)d_out;

    const int N    = in_sizes[0] / 256;     // 50000 (< 65536: u16 pack valid)
    const int E    = in_sizes[1] / 2;       // 1600000
    const int HOPS = in_sizes[10] / 256;    // 3
    const int O    = in_sizes[13];          // 40
    const int SETS = HOPS + 1;              // edge sets: [ei, hop0..2]
    const int NB   = HOPS + 2;              // branches
    const int B    = (N + 255) >> 8;        // buckets (<= 256)

    // workspace carve (256B aligned)
    char* p = (char*)d_ws;
    auto carve = [&](size_t bytes) { char* r = p; p += (bytes + 255) & ~(size_t)255; return r; };
    u16* x16  = (u16*)carve((size_t)N * 256 * 2);
    u16* hA   = (u16*)carve((size_t)N * 256 * 2);
    u16* hB   = (u16*)carve((size_t)N * 256 * 2);
    u16* ebuf = (u16*)carve((size_t)N * 256 * 2);
    u16* wt   = (u16*)carve((size_t)(3 + HOPS) * 256 * 256 * 2); // [mlp,e1,e2,hop0..]
    u16* wct  = (u16*)carve((size_t)NB * 48 * 256 * 2);
    float* mask = (float*)carve(256);
    float* dinv = (float*)carve((size_t)SETS * N * 4);
    int* rp   = (int*)carve((size_t)SETS * (N + 1) * 4);
    int* bcnt = (int*)carve((size_t)SETS * BMAX * 4);
    int* bbase = (int*)carve((size_t)SETS * BMAX * 4);
    int* colAll = (int*)carve((size_t)SETS * E * 4);
    u32* binned = (u32*)hA;   // alias hA+hB (51.2MB >= SETS*BMAX*BCAP*4 = 50.3MB);
                              // binned lifetime ends before any GEMM writes hA/hB

    // packing + mask
    softmax_small<<<1, 64, 0, stream>>>(att, mask, NB);
    {
        long n = (long)N * 256;
        pack_bf16<<<(int)((n / 4 + 255) / 256), 256, 0, stream>>>(x, x16, n);
    }
    {
        dim3 g(256, 3 + HOPS);
        pack_wt_all<<<g, 256, 0, stream>>>(W_mlp, We1, We2, Wh, wt);
    }
    {
        int tot = NB * 48 * 256;
        pack_wct<<<(tot + 255) / 256, 256, 0, stream>>>(Wc, wct, O, NB);
    }

    // bucket-local CSR build
    hipMemsetAsync(bcnt, 0, (size_t)SETS * BMAX * 4, stream);
    {
        dim3 g((E + BINCHUNK - 1) / BINCHUNK, SETS);
        bin_edges<<<g, 256, 0, stream>>>(ei, nei, E, B, bcnt, binned);
    }
    bscan<<<SETS, 256, 0, stream>>>(bcnt, bbase, rp, N, E, B);
    {
        dim3 g(B, SETS);
        bucket_build<<<g, 256, 0, stream>>>(binned, bcnt, bbase, rp, dinv, colAll, E, N);
    }

    dim3 gg((N + 127) / 128, 2);
    const int gl = (N + 63) / 64;
    const int ga = (N + 3) / 4;

    // mlp branch -> Wc block NB-1 (FIRST: writes out = acc + bc)
    gemm_k256<0><<<gg, 256, 0, stream>>>(x16, wt, hB, b_mlp, nullptr, mask, 0, N);
    logit_gemm<1><<<gl, 256, 0, stream>>>(hB, wct + (size_t)(NB - 1) * 48 * 256, bc, out, N);

    // hop branches -> Wc blocks 0..HOPS-1, mask[i+1]
    for (int i = 0; i < HOPS; ++i) {
        int s = i + 1;
        gemm_k256<1><<<gg, 256, 0, stream>>>(x16, wt + (size_t)(3 + i) * 65536, hA,
                                             nullptr, dinv + (size_t)s * N, nullptr, 0, N);
        agg_gcn<<<ga, 256, 0, stream>>>(hA, rp + (size_t)s * (N + 1), colAll + (size_t)s * E,
                                        dinv + (size_t)s * N, bh + (size_t)i * 256,
                                        mask, i + 1, hB, N);
        logit_gemm<0><<<gl, 256, 0, stream>>>(hB, wct + (size_t)i * 48 * 256, bc, out, N);
    }

    // e branch: gcn1 (no mask) -> gcn2 (*mask[1]) -> Wc block HOPS
    gemm_k256<1><<<gg, 256, 0, stream>>>(x16, wt + 1 * 65536, hA, nullptr, dinv, nullptr, 0, N);
    agg_gcn<<<ga, 256, 0, stream>>>(hA, rp, colAll, dinv, be1, mask, -1, ebuf, N);
    gemm_k256<1><<<gg, 256, 0, stream>>>(ebuf, wt + 2 * 65536, hA, nullptr, dinv, nullptr, 0, N);
    agg_gcn<<<ga, 256, 0, stream>>>(hA, rp, colAll, dinv, be2, mask, 1, hB, N);
    logit_gemm<0><<<gl, 256, 0, stream>>>(hB, wct + (size_t)HOPS * 48 * 256, bc, out, N);

    // final log-softmax in place on d_out
    logsoftmax_k<<<(N + 3) / 4, 256, 0, stream>>>(out, N, O);
}